// Round 2
// baseline (616.133 us; speedup 1.0000x reference)
//
#include <hip/hip_runtime.h>
#include <hip/hip_bf16.h>

// GCN pipeline on MI355X — all tensors fp32 (per harness contract), indices int32.
//
//   bufA = leaky(x @ W_in + b_in)                  (GEMM1, K=239 scalar-A path)
//   build dst-CSR + dinv once (shared by both convs)
//   bufB = bufA @ W_g ; bufA = agg(bufB) + b_g     (conv1: CSR pull, no atomics)
//   bufB = bufA @ W_g ; bufA = agg(bufB) + b_g     (conv2)
//   bufB = leaky(bufA @ W_o1 + b_o1)
//   out  = bufB @ W_o2 + b_o2                      (float2 store)

// ---------------- CSR build ----------------

__global__ __launch_bounds__(256) void zero_k(int* __restrict__ p, int n) {
  int i = blockIdx.x * 256 + threadIdx.x;
  if (i < n) p[i] = 0;
}

__global__ __launch_bounds__(256) void hist_k(const int* __restrict__ dst, int* __restrict__ cnt, int E) {
  int e = blockIdx.x * 256 + threadIdx.x;
  if (e < E) atomicAdd(&cnt[dst[e]], 1);
}

__global__ __launch_bounds__(256) void dinv_k(const int* __restrict__ cnt, float* __restrict__ dinv, int N) {
  int i = blockIdx.x * 256 + threadIdx.x;
  if (i < N) dinv[i] = rsqrtf((float)cnt[i] + 1.0f);
}

// block scans 1024 elements (4/thread); block-exclusive values to rp, block total to bsum
__global__ __launch_bounds__(256) void scan1_k(const int* __restrict__ cnt, int* __restrict__ rp,
                                               int* __restrict__ bsum, int N) {
  __shared__ int sd[256];
  int t = threadIdx.x;
  int base = blockIdx.x * 1024 + t * 4;
  int v0 = (base + 0 < N) ? cnt[base + 0] : 0;
  int v1 = (base + 1 < N) ? cnt[base + 1] : 0;
  int v2 = (base + 2 < N) ? cnt[base + 2] : 0;
  int v3 = (base + 3 < N) ? cnt[base + 3] : 0;
  int ts = v0 + v1 + v2 + v3;
  sd[t] = ts;
  __syncthreads();
  for (int off = 1; off < 256; off <<= 1) {
    int y = (t >= off) ? sd[t - off] : 0;
    __syncthreads();
    sd[t] += y;
    __syncthreads();
  }
  int x = sd[t] - ts;  // exclusive base for this thread
  if (t == 255) bsum[blockIdx.x] = sd[255];
  if (base + 0 < N) rp[base + 0] = x; x += v0;
  if (base + 1 < N) rp[base + 1] = x; x += v1;
  if (base + 2 < N) rp[base + 2] = x; x += v2;
  if (base + 3 < N) rp[base + 3] = x;
}

// single block: exclusive scan of bsum[0..NB) in place (NB <= 1024)
__global__ __launch_bounds__(256) void scan2_k(int* __restrict__ bsum, int NB) {
  __shared__ int sd[256];
  int t = threadIdx.x;
  int base = t * 4;
  int v0 = (base + 0 < NB) ? bsum[base + 0] : 0;
  int v1 = (base + 1 < NB) ? bsum[base + 1] : 0;
  int v2 = (base + 2 < NB) ? bsum[base + 2] : 0;
  int v3 = (base + 3 < NB) ? bsum[base + 3] : 0;
  int ts = v0 + v1 + v2 + v3;
  sd[t] = ts;
  __syncthreads();
  for (int off = 1; off < 256; off <<= 1) {
    int y = (t >= off) ? sd[t - off] : 0;
    __syncthreads();
    sd[t] += y;
    __syncthreads();
  }
  int x = sd[t] - ts;
  if (base + 0 < NB) bsum[base + 0] = x; x += v0;
  if (base + 1 < NB) bsum[base + 1] = x; x += v1;
  if (base + 2 < NB) bsum[base + 2] = x; x += v2;
  if (base + 3 < NB) bsum[base + 3] = x;
}

// add block offsets; copy to pos[] for the fill pass; set rp[N]=E
__global__ __launch_bounds__(256) void scan3_k(int* __restrict__ rp, int* __restrict__ pos,
                                               const int* __restrict__ bsum, int N, int E) {
  int i = blockIdx.x * 256 + threadIdx.x;
  if (i < N) {
    int v = rp[i] + bsum[i >> 10];
    rp[i] = v;
    pos[i] = v;
  }
  if (i == 0) rp[N] = E;
}

__global__ __launch_bounds__(256) void fill_k(const int* __restrict__ src, const int* __restrict__ dst,
                                              int* __restrict__ pos, int* __restrict__ col, int E) {
  int e = blockIdx.x * 256 + threadIdx.x;
  if (e < E) {
    int d = dst[e];
    int idx = atomicAdd(&pos[d], 1);
    col[idx] = src[e];
  }
}

// ---------------- GEMM: C[N,128] = A[N,K] @ W[K,128] (+bias, +leaky) ----------------
// BM=128, BN=128(full), BK=16, 256 threads, 8x8 outputs/thread, fp32 VALU.
// VECA: use float4 A loads (requires K % 16 == 0); otherwise guarded scalar loads.

template <bool VECA, bool BIAS_ACT>
__global__ __launch_bounds__(256) void gemm_k(const float* __restrict__ A,
                                              const float* __restrict__ W,
                                              const float* __restrict__ bias,
                                              float* __restrict__ C, int N, int K) {
  __shared__ float As[16][128];  // [k][row]  (transposed A tile)
  __shared__ float Ws[16][128];  // [k][col]
  const int tid = threadIdx.x;
  const int tc = tid & 15;   // col group: cols 8*tc..8*tc+7
  const int tr = tid >> 4;   // row group: rows 8*tr..8*tr+7
  const int m0 = blockIdx.x * 128;

  float acc[8][8] = {};

  const int lrow = tid >> 1;         // 0..127
  const int lk0 = (tid & 1) * 8;     // 0 or 8
  const int arow = m0 + lrow;

  const int wro = tid >> 4;          // 0..15 (W tile row)
  const int wcol = (tid & 15) * 8;   // 0..120

  for (int k0 = 0; k0 < K; k0 += 16) {
    // --- stage A tile (transposed) ---
    float av[8] = {0.f, 0.f, 0.f, 0.f, 0.f, 0.f, 0.f, 0.f};
    if (arow < N) {
      const float* ap = A + (size_t)arow * K;
      if constexpr (VECA) {
        float4 p0 = *(const float4*)(ap + k0 + lk0);
        float4 p1 = *(const float4*)(ap + k0 + lk0 + 4);
        av[0] = p0.x; av[1] = p0.y; av[2] = p0.z; av[3] = p0.w;
        av[4] = p1.x; av[5] = p1.y; av[6] = p1.z; av[7] = p1.w;
      } else {
#pragma unroll
        for (int j = 0; j < 8; ++j) {
          int kk = k0 + lk0 + j;
          av[j] = (kk < K) ? ap[kk] : 0.f;
        }
      }
    }
#pragma unroll
    for (int j = 0; j < 8; ++j) As[lk0 + j][lrow] = av[j];

    // --- stage W tile ---  (row stride 128 floats = 512 B, always 16B-aligned)
    {
      int kk = k0 + wro;
      float4 w0 = make_float4(0.f, 0.f, 0.f, 0.f);
      float4 w1 = make_float4(0.f, 0.f, 0.f, 0.f);
      if (kk < K) {
        const float* wp = W + (size_t)kk * 128 + wcol;
        w0 = *(const float4*)wp;
        w1 = *(const float4*)(wp + 4);
      }
      *(float4*)&Ws[wro][wcol] = w0;
      *(float4*)&Ws[wro][wcol + 4] = w1;
    }
    __syncthreads();

#pragma unroll
    for (int kk = 0; kk < 16; ++kk) {
      float4 a0 = *(const float4*)&As[kk][8 * tr];
      float4 a1 = *(const float4*)&As[kk][8 * tr + 4];
      float4 w0 = *(const float4*)&Ws[kk][8 * tc];
      float4 w1 = *(const float4*)&Ws[kk][8 * tc + 4];
      float a[8] = {a0.x, a0.y, a0.z, a0.w, a1.x, a1.y, a1.z, a1.w};
      float w[8] = {w0.x, w0.y, w0.z, w0.w, w1.x, w1.y, w1.z, w1.w};
#pragma unroll
      for (int r = 0; r < 8; ++r)
#pragma unroll
        for (int c = 0; c < 8; ++c) acc[r][c] = fmaf(a[r], w[c], acc[r][c]);
    }
    __syncthreads();
  }

  float bv[8];
  if (BIAS_ACT) {
#pragma unroll
    for (int c = 0; c < 8; ++c) bv[c] = bias[8 * tc + c];
  }
#pragma unroll
  for (int r = 0; r < 8; ++r) {
    int row = m0 + 8 * tr + r;
    if (row < N) {
      float o[8];
#pragma unroll
      for (int c = 0; c < 8; ++c) {
        float v = acc[r][c];
        if (BIAS_ACT) {
          v += bv[c];
          v = v >= 0.f ? v : 0.01f * v;
        }
        o[c] = v;
      }
      float* cp = C + (size_t)row * 128 + 8 * tc;
      *(float4*)cp = make_float4(o[0], o[1], o[2], o[3]);
      *(float4*)(cp + 4) = make_float4(o[4], o[5], o[6], o[7]);
    }
  }
}

// ---------------- CSR-pull aggregation: O[i] = sum_{e:dst=i} T[src]*dinv[src]*dinv[i]
//                  + T[i]*dinv[i]^2 + bias.  32 lanes/node, float4/lane.

__global__ __launch_bounds__(256) void agg_k(const float* __restrict__ T, const float* __restrict__ dinv,
                                             const int* __restrict__ rp, const int* __restrict__ col,
                                             const float* __restrict__ bias,
                                             float* __restrict__ O, int N) {
  int lane = threadIdx.x & 31;
  int node = blockIdx.x * 8 + (threadIdx.x >> 5);
  if (node >= N) return;
  float di = dinv[node];
  const float4* T4 = (const float4*)T;
  float4 s = T4[(size_t)node * 32 + lane];
  float sw = di * di;
  float ax = s.x * sw, ay = s.y * sw, az = s.z * sw, aw = s.w * sw;
  int e1 = rp[node + 1];
  for (int e = rp[node]; e < e1; ++e) {
    int sc = col[e];
    float w = dinv[sc] * di;
    float4 v = T4[(size_t)sc * 32 + lane];
    ax = fmaf(v.x, w, ax);
    ay = fmaf(v.y, w, ay);
    az = fmaf(v.z, w, az);
    aw = fmaf(v.w, w, aw);
  }
  int c0 = lane * 4;
  ax += bias[c0 + 0];
  ay += bias[c0 + 1];
  az += bias[c0 + 2];
  aw += bias[c0 + 3];
  ((float4*)O)[(size_t)node * 32 + lane] = make_float4(ax, ay, az, aw);
}

// ---------------- final: out[N,2] = A[N,128] @ W2[128,2] + b2 ----------------
// 4 threads/row, 32 k each, shfl-reduce, float2 store.

__global__ __launch_bounds__(256) void out_k(const float* __restrict__ A,
                                             const float* __restrict__ W2,
                                             const float* __restrict__ b2,
                                             float* __restrict__ out, int N) {
  __shared__ float Ws[256];  // 128x2 row-major
  int tid = threadIdx.x;
  Ws[tid] = W2[tid];
  __syncthreads();
  int row = blockIdx.x * 64 + (tid >> 2);
  int seg = tid & 3;
  float acc0 = 0.f, acc1 = 0.f;
  if (row < N) {
    const float4* ap = (const float4*)(A + (size_t)row * 128 + seg * 32);
#pragma unroll
    for (int j = 0; j < 8; ++j) {
      float4 v = ap[j];
      int k = seg * 32 + j * 4;
      acc0 = fmaf(v.x, Ws[(k + 0) * 2 + 0], acc0); acc1 = fmaf(v.x, Ws[(k + 0) * 2 + 1], acc1);
      acc0 = fmaf(v.y, Ws[(k + 1) * 2 + 0], acc0); acc1 = fmaf(v.y, Ws[(k + 1) * 2 + 1], acc1);
      acc0 = fmaf(v.z, Ws[(k + 2) * 2 + 0], acc0); acc1 = fmaf(v.z, Ws[(k + 2) * 2 + 1], acc1);
      acc0 = fmaf(v.w, Ws[(k + 3) * 2 + 0], acc0); acc1 = fmaf(v.w, Ws[(k + 3) * 2 + 1], acc1);
    }
  }
  acc0 += __shfl_xor(acc0, 1); acc0 += __shfl_xor(acc0, 2);
  acc1 += __shfl_xor(acc1, 1); acc1 += __shfl_xor(acc1, 2);
  if (seg == 0 && row < N) {
    *((float2*)(out + (size_t)row * 2)) = make_float2(acc0 + b2[0], acc1 + b2[1]);
  }
}

// ---------------- launch ----------------

extern "C" void kernel_launch(void* const* d_in, const int* in_sizes, int n_in,
                              void* d_out, int out_size, void* d_ws, size_t ws_size,
                              hipStream_t stream) {
  const float* x = (const float*)d_in[0];
  const int* ei = (const int*)d_in[1];
  const float* W_in = (const float*)d_in[3];
  const float* b_in = (const float*)d_in[4];
  const float* W_g  = (const float*)d_in[5];
  const float* b_g  = (const float*)d_in[6];
  const float* W_o1 = (const float*)d_in[7];
  const float* b_o1 = (const float*)d_in[8];
  const float* W_o2 = (const float*)d_in[9];
  const float* b_o2 = (const float*)d_in[10];

  const int D = in_sizes[4];           // 128
  const int ND = in_sizes[3] / D;      // 239
  const int N = in_sizes[0] / ND;      // 100000
  const int E = in_sizes[2];           // 640000
  const int* src = ei;
  const int* dst = ei + E;

  // workspace layout (fp32/int32): 2*N*D + N + N + (N+1) + 1024 + E elems (~106 MB)
  float* bufA = (float*)d_ws;
  float* bufB = bufA + (size_t)N * D;
  float* dinv = bufB + (size_t)N * D;
  int* cnt  = (int*)(dinv + N);
  int* rp   = cnt + N;
  int* bsum = rp + (N + 1);
  int* col  = bsum + 1024;

  const int NB = (N + 1023) / 1024;

  // CSR + dinv (shared by both convs)
  zero_k<<<(N + 255) / 256, 256, 0, stream>>>(cnt, N);
  hist_k<<<(E + 255) / 256, 256, 0, stream>>>(dst, cnt, E);
  dinv_k<<<(N + 255) / 256, 256, 0, stream>>>(cnt, dinv, N);
  scan1_k<<<NB, 256, 0, stream>>>(cnt, rp, bsum, N);
  scan2_k<<<1, 256, 0, stream>>>(bsum, NB);
  scan3_k<<<(N + 255) / 256, 256, 0, stream>>>(rp, cnt /*pos*/, bsum, N, E);
  fill_k<<<(E + 255) / 256, 256, 0, stream>>>(src, dst, cnt, col, E);

  const int gblocks = (N + 127) / 128;
  // h0 = leaky(x @ W_in + b_in)      (K=239 -> scalar A path)
  gemm_k<false, true><<<gblocks, 256, 0, stream>>>(x, W_in, b_in, bufA, N, ND);
  // conv1
  gemm_k<true, false><<<gblocks, 256, 0, stream>>>(bufA, W_g, nullptr, bufB, N, D);
  agg_k<<<(N + 7) / 8, 256, 0, stream>>>(bufB, dinv, rp, col, b_g, bufA, N);
  // conv2
  gemm_k<true, false><<<gblocks, 256, 0, stream>>>(bufA, W_g, nullptr, bufB, N, D);
  agg_k<<<(N + 7) / 8, 256, 0, stream>>>(bufB, dinv, rp, col, b_g, bufA, N);
  // h3 = leaky(h @ W_o1 + b_o1)
  gemm_k<true, true><<<gblocks, 256, 0, stream>>>(bufA, W_o1, b_o1, bufB, N, D);
  // out = h3 @ W_o2 + b_o2
  out_k<<<(N + 63) / 64, 256, 0, stream>>>(bufB, W_o2, b_o2, (float*)d_out, N);
}

// Round 3
// 474.616 us; speedup vs baseline: 1.2982x; 1.2982x over previous
//
#include <hip/hip_runtime.h>
#include <hip/hip_bf16.h>

// GCN pipeline on MI355X — MFMA bf16 GEMMs, fp32 accumulate/aggregation.
//
//   xb  = bf16(x) padded K 239->256              (cvtx_k)
//   Wt* = bf16(W^T) (B-frag wants k-contiguous)  (wtr_k x3)
//   CSR build (shared by both convs)
//   hbf  = leaky(xb @ W_in + b_in)      bf16     (mgemm MODE=2, K=256)
//   bufF = hbf @ W_g                    f32      (mgemm MODE=0, K=128)
//   hbf  = agg(bufF) + b_g              bf16     (agg_k)
//   bufF = hbf @ W_g ; hbf = agg+b_g             (conv 2)
//   bufF = leaky(hbf @ W_o1 + b_o1)     f32      (mgemm MODE=1)
//   out  = bufF @ W_o2 + b_o2           f32      (out_k, VALU)

typedef __attribute__((ext_vector_type(8))) __bf16 bf16x8;
typedef __attribute__((ext_vector_type(4))) float f32x4;

// ---------------- converters ----------------

__global__ __launch_bounds__(256) void cvtx_k(const float* __restrict__ x, ushort* __restrict__ xb,
                                              int N, int K, int Kp) {
  int t = blockIdx.x * 256 + threadIdx.x;
  int row = t >> 5;           // 32 threads per row, 8 cols each (Kp=256)
  int col0 = (t & 31) * 8;
  if (row >= N) return;
  union { ushort4 v[2]; __hip_bfloat16 h[8]; } u;
#pragma unroll
  for (int j = 0; j < 8; ++j) {
    int c = col0 + j;
    float v = (c < K) ? x[(size_t)row * K + c] : 0.f;
    u.h[j] = __float2bfloat16(v);
  }
  *(ushort4*)&xb[(size_t)row * Kp + col0] = u.v[0];
  *(ushort4*)&xb[(size_t)row * Kp + col0 + 4] = u.v[1];
}

// W [K][128] f32 -> Wt [128][Kp] bf16 (transpose + convert, zero-pad k>=K)
__global__ __launch_bounds__(256) void wtr_k(const float* __restrict__ W, ushort* __restrict__ Wt,
                                             int K, int Kp) {
  int idx = blockIdx.x * 256 + threadIdx.x;
  if (idx >= 128 * Kp) return;
  int n = idx / Kp, k = idx % Kp;
  float v = (k < K) ? W[(size_t)k * 128 + n] : 0.f;
  __hip_bfloat16 h = __float2bfloat16(v);
  Wt[idx] = *(ushort*)&h;
}

// ---------------- CSR build ----------------

__global__ __launch_bounds__(256) void zero_k(int* __restrict__ p, int n) {
  int i = blockIdx.x * 256 + threadIdx.x;
  if (i < n) p[i] = 0;
}

__global__ __launch_bounds__(256) void hist_k(const int* __restrict__ dst, int* __restrict__ cnt, int E) {
  int e = blockIdx.x * 256 + threadIdx.x;
  if (e < E) atomicAdd(&cnt[dst[e]], 1);
}

__global__ __launch_bounds__(256) void dinv_k(const int* __restrict__ cnt, float* __restrict__ dinv, int N) {
  int i = blockIdx.x * 256 + threadIdx.x;
  if (i < N) dinv[i] = rsqrtf((float)cnt[i] + 1.0f);
}

__global__ __launch_bounds__(256) void scan1_k(const int* __restrict__ cnt, int* __restrict__ rp,
                                               int* __restrict__ bsum, int N) {
  __shared__ int sd[256];
  int t = threadIdx.x;
  int base = blockIdx.x * 1024 + t * 4;
  int v0 = (base + 0 < N) ? cnt[base + 0] : 0;
  int v1 = (base + 1 < N) ? cnt[base + 1] : 0;
  int v2 = (base + 2 < N) ? cnt[base + 2] : 0;
  int v3 = (base + 3 < N) ? cnt[base + 3] : 0;
  int ts = v0 + v1 + v2 + v3;
  sd[t] = ts;
  __syncthreads();
  for (int off = 1; off < 256; off <<= 1) {
    int y = (t >= off) ? sd[t - off] : 0;
    __syncthreads();
    sd[t] += y;
    __syncthreads();
  }
  int x = sd[t] - ts;
  if (t == 255) bsum[blockIdx.x] = sd[255];
  if (base + 0 < N) rp[base + 0] = x; x += v0;
  if (base + 1 < N) rp[base + 1] = x; x += v1;
  if (base + 2 < N) rp[base + 2] = x; x += v2;
  if (base + 3 < N) rp[base + 3] = x;
}

__global__ __launch_bounds__(256) void scan2_k(int* __restrict__ bsum, int NB) {
  __shared__ int sd[256];
  int t = threadIdx.x;
  int base = t * 4;
  int v0 = (base + 0 < NB) ? bsum[base + 0] : 0;
  int v1 = (base + 1 < NB) ? bsum[base + 1] : 0;
  int v2 = (base + 2 < NB) ? bsum[base + 2] : 0;
  int v3 = (base + 3 < NB) ? bsum[base + 3] : 0;
  int ts = v0 + v1 + v2 + v3;
  sd[t] = ts;
  __syncthreads();
  for (int off = 1; off < 256; off <<= 1) {
    int y = (t >= off) ? sd[t - off] : 0;
    __syncthreads();
    sd[t] += y;
    __syncthreads();
  }
  int x = sd[t] - ts;
  if (base + 0 < NB) bsum[base + 0] = x; x += v0;
  if (base + 1 < NB) bsum[base + 1] = x; x += v1;
  if (base + 2 < NB) bsum[base + 2] = x; x += v2;
  if (base + 3 < NB) bsum[base + 3] = x;
}

__global__ __launch_bounds__(256) void scan3_k(int* __restrict__ rp, int* __restrict__ pos,
                                               const int* __restrict__ bsum, int N, int E) {
  int i = blockIdx.x * 256 + threadIdx.x;
  if (i < N) {
    int v = rp[i] + bsum[i >> 10];
    rp[i] = v;
    pos[i] = v;
  }
  if (i == 0) rp[N] = E;
}

__global__ __launch_bounds__(256) void fill_k(const int* __restrict__ src, const int* __restrict__ dst,
                                              int* __restrict__ pos, int* __restrict__ col, int E) {
  int e = blockIdx.x * 256 + threadIdx.x;
  if (e < E) {
    int d = dst[e];
    int idx = atomicAdd(&pos[d], 1);
    col[idx] = src[e];
  }
}

// ---------------- MFMA GEMM: C[N,128] = A[N,Kg](bf16) @ Wt^T (Wt bf16 [128][Kg]) ----------------
// 128x128 tile, 4 waves, each wave 32 rows x 128 cols = 2x8 tiles of 16x16x32.
// LDS: XOR-swizzled 16B chunks (2-way conflicts only = free). 64 KB total -> 2 blocks/CU.
// MODE: 0 = f32 out, 1 = f32 + bias + leaky, 2 = bf16 + bias + leaky.

template <int MODE>
__global__ __launch_bounds__(256) void mgemm_k(const ushort* __restrict__ A,
                                               const ushort* __restrict__ Wt,
                                               const float* __restrict__ bias,
                                               void* __restrict__ C, int N, int Kg) {
  __shared__ uint4 Al[128 * 16];  // [row][chunk^swz], chunk = 8 bf16 = 16 B
  __shared__ uint4 Wl[128 * 16];
  const int tid = threadIdx.x;
  const int wave = tid >> 6;
  const int lane = tid & 63;
  const int l16 = lane & 15;
  const int quad = lane >> 4;
  const int m0 = blockIdx.x * 128;

  f32x4 acc[2][8] = {};

  const int r_s = tid >> 4;  // staging row within group of 16
  const int j8 = tid & 15;   // staging chunk index
  const int nchunks = Kg >> 7;

  for (int kc = 0; kc < nchunks; ++kc) {
    const int kbase = kc << 7;
    if (kc) __syncthreads();
#pragma unroll
    for (int it = 0; it < 8; ++it) {
      int m = it * 16 + r_s;
      uint4 v = *(const uint4*)(A + (size_t)(m0 + m) * Kg + kbase + j8 * 8);
      Al[m * 16 + (j8 ^ r_s)] = v;
    }
#pragma unroll
    for (int it = 0; it < 8; ++it) {
      int n = it * 16 + r_s;
      uint4 v = *(const uint4*)(Wt + (size_t)n * Kg + kbase + j8 * 8);
      Wl[n * 16 + (j8 ^ r_s)] = v;
    }
    __syncthreads();
#pragma unroll
    for (int s = 0; s < 4; ++s) {
      const int j = s * 4 + quad;          // k-chunk this quad reads
      const int swz = j ^ l16;
      bf16x8 a0 = *(const bf16x8*)&Al[(wave * 32 + l16) * 16 + swz];
      bf16x8 a1 = *(const bf16x8*)&Al[(wave * 32 + 16 + l16) * 16 + swz];
#pragma unroll
      for (int c = 0; c < 8; ++c) {
        bf16x8 b = *(const bf16x8*)&Wl[(c * 16 + l16) * 16 + swz];
        acc[0][c] = __builtin_amdgcn_mfma_f32_16x16x32_bf16(a0, b, acc[0][c], 0, 0, 0);
        acc[1][c] = __builtin_amdgcn_mfma_f32_16x16x32_bf16(a1, b, acc[1][c], 0, 0, 0);
      }
    }
  }

  // epilogue: D layout col = lane&15, row = quad*4 + reg (within 16x16 tile)
  float bv[8];
  if (MODE) {
#pragma unroll
    for (int c = 0; c < 8; ++c) bv[c] = bias[c * 16 + l16];
  }
#pragma unroll
  for (int r = 0; r < 2; ++r) {
#pragma unroll
    for (int reg = 0; reg < 4; ++reg) {
      int row = m0 + wave * 32 + r * 16 + quad * 4 + reg;
      if (row < N) {
#pragma unroll
        for (int c = 0; c < 8; ++c) {
          float v = acc[r][c][reg];
          if (MODE) {
            v += bv[c];
            v = v >= 0.f ? v : 0.01f * v;
          }
          int colj = c * 16 + l16;
          if (MODE == 2) {
            __hip_bfloat16 h = __float2bfloat16(v);
            ((ushort*)C)[(size_t)row * 128 + colj] = *(ushort*)&h;
          } else {
            ((float*)C)[(size_t)row * 128 + colj] = v;
          }
        }
      }
    }
  }
}

// ---------------- CSR-pull aggregation -> bf16 out ----------------
// O[i] = sum_{e:dst=i} T[src]*dinv[src]*dinv[i] + T[i]*dinv[i]^2 + bias

__global__ __launch_bounds__(256) void agg_k(const float* __restrict__ T, const float* __restrict__ dinv,
                                             const int* __restrict__ rp, const int* __restrict__ col,
                                             const float* __restrict__ bias,
                                             ushort* __restrict__ O, int N) {
  int lane = threadIdx.x & 31;
  int node = blockIdx.x * 8 + (threadIdx.x >> 5);
  if (node >= N) return;
  float di = dinv[node];
  const float4* T4 = (const float4*)T;
  float4 s = T4[(size_t)node * 32 + lane];
  float sw = di * di;
  float ax = s.x * sw, ay = s.y * sw, az = s.z * sw, aw = s.w * sw;
  int e1 = rp[node + 1];
  for (int e = rp[node]; e < e1; ++e) {
    int sc = col[e];
    float w = dinv[sc] * di;
    float4 v = T4[(size_t)sc * 32 + lane];
    ax = fmaf(v.x, w, ax);
    ay = fmaf(v.y, w, ay);
    az = fmaf(v.z, w, az);
    aw = fmaf(v.w, w, aw);
  }
  int c0 = lane * 4;
  union { ushort4 v; __hip_bfloat16 h[4]; } uo;
  uo.h[0] = __float2bfloat16(ax + bias[c0 + 0]);
  uo.h[1] = __float2bfloat16(ay + bias[c0 + 1]);
  uo.h[2] = __float2bfloat16(az + bias[c0 + 2]);
  uo.h[3] = __float2bfloat16(aw + bias[c0 + 3]);
  ((ushort4*)O)[(size_t)node * 32 + lane] = uo.v;
}

// ---------------- final: out[N,2] = A[N,128] @ W2[128,2] + b2 (fp32 VALU) ----------------

__global__ __launch_bounds__(256) void out_k(const float* __restrict__ A,
                                             const float* __restrict__ W2,
                                             const float* __restrict__ b2,
                                             float* __restrict__ out, int N) {
  __shared__ float Ws[256];
  int tid = threadIdx.x;
  Ws[tid] = W2[tid];
  __syncthreads();
  int row = blockIdx.x * 64 + (tid >> 2);
  int seg = tid & 3;
  float acc0 = 0.f, acc1 = 0.f;
  if (row < N) {
    const float4* ap = (const float4*)(A + (size_t)row * 128 + seg * 32);
#pragma unroll
    for (int j = 0; j < 8; ++j) {
      float4 v = ap[j];
      int k = seg * 32 + j * 4;
      acc0 = fmaf(v.x, Ws[(k + 0) * 2 + 0], acc0); acc1 = fmaf(v.x, Ws[(k + 0) * 2 + 1], acc1);
      acc0 = fmaf(v.y, Ws[(k + 1) * 2 + 0], acc0); acc1 = fmaf(v.y, Ws[(k + 1) * 2 + 1], acc1);
      acc0 = fmaf(v.z, Ws[(k + 2) * 2 + 0], acc0); acc1 = fmaf(v.z, Ws[(k + 2) * 2 + 1], acc1);
      acc0 = fmaf(v.w, Ws[(k + 3) * 2 + 0], acc0); acc1 = fmaf(v.w, Ws[(k + 3) * 2 + 1], acc1);
    }
  }
  acc0 += __shfl_xor(acc0, 1); acc0 += __shfl_xor(acc0, 2);
  acc1 += __shfl_xor(acc1, 1); acc1 += __shfl_xor(acc1, 2);
  if (seg == 0 && row < N) {
    *((float2*)(out + (size_t)row * 2)) = make_float2(acc0 + b2[0], acc1 + b2[1]);
  }
}

// ---------------- launch ----------------

extern "C" void kernel_launch(void* const* d_in, const int* in_sizes, int n_in,
                              void* d_out, int out_size, void* d_ws, size_t ws_size,
                              hipStream_t stream) {
  const float* x = (const float*)d_in[0];
  const int* ei = (const int*)d_in[1];
  const float* W_in = (const float*)d_in[3];
  const float* b_in = (const float*)d_in[4];
  const float* W_g  = (const float*)d_in[5];
  const float* b_g  = (const float*)d_in[6];
  const float* W_o1 = (const float*)d_in[7];
  const float* b_o1 = (const float*)d_in[8];
  const float* W_o2 = (const float*)d_in[9];
  const float* b_o2 = (const float*)d_in[10];

  const int D = in_sizes[4];        // 128
  const int ND = in_sizes[3] / D;   // 239
  const int N = in_sizes[0] / ND;   // 100000
  const int E = in_sizes[2];        // 640000
  const int* src = ei;
  const int* dst = ei + E;

  const int N_pad = ((N + 127) / 128) * 128;
  const size_t np = (size_t)N_pad;
  const int KP1 = 256;  // 239 padded

  // workspace layout (~81 MB)
  ushort* xb   = (ushort*)d_ws;                       // np*256 bf16 (aliases bufF)
  float*  bufF = (float*)d_ws;                        // np*128 f32 (same bytes)
  ushort* hbf  = (ushort*)((char*)d_ws + np * 512);   // np*128 bf16
  ushort* Wt_in = hbf + np * 128;                     // 128*256 bf16
  ushort* Wt_g  = Wt_in + 128 * 256;                  // 128*128
  ushort* Wt_o1 = Wt_g + 128 * 128;                   // 128*128
  float* dinv = (float*)(Wt_o1 + 128 * 128);
  int* cnt  = (int*)(dinv + N);
  int* rp   = cnt + N;
  int* bsum = rp + (N + 1);
  int* col  = bsum + 1024;

  const int NB = (N + 1023) / 1024;

  // converters
  cvtx_k<<<(N * 32 + 255) / 256, 256, 0, stream>>>(x, xb, N, ND, KP1);
  wtr_k<<<(128 * KP1 + 255) / 256, 256, 0, stream>>>(W_in, Wt_in, ND, KP1);
  wtr_k<<<(128 * 128 + 255) / 256, 256, 0, stream>>>(W_g, Wt_g, 128, 128);
  wtr_k<<<(128 * 128 + 255) / 256, 256, 0, stream>>>(W_o1, Wt_o1, 128, 128);

  // CSR + dinv (shared by both convs)
  zero_k<<<(N + 255) / 256, 256, 0, stream>>>(cnt, N);
  hist_k<<<(E + 255) / 256, 256, 0, stream>>>(dst, cnt, E);
  dinv_k<<<(N + 255) / 256, 256, 0, stream>>>(cnt, dinv, N);
  scan1_k<<<NB, 256, 0, stream>>>(cnt, rp, bsum, N);
  scan2_k<<<1, 256, 0, stream>>>(bsum, NB);
  scan3_k<<<(N + 255) / 256, 256, 0, stream>>>(rp, cnt /*pos*/, bsum, N, E);
  fill_k<<<(E + 255) / 256, 256, 0, stream>>>(src, dst, cnt, col, E);

  const int gblocks = N_pad / 128;
  // h0 = leaky(x @ W_in + b_in) -> bf16
  mgemm_k<2><<<gblocks, 256, 0, stream>>>(xb, Wt_in, b_in, hbf, N, KP1);
  // conv1
  mgemm_k<0><<<gblocks, 256, 0, stream>>>(hbf, Wt_g, nullptr, bufF, N, 128);
  agg_k<<<(N + 7) / 8, 256, 0, stream>>>(bufF, dinv, rp, col, b_g, hbf, N);
  // conv2
  mgemm_k<0><<<gblocks, 256, 0, stream>>>(hbf, Wt_g, nullptr, bufF, N, 128);
  agg_k<<<(N + 7) / 8, 256, 0, stream>>>(bufF, dinv, rp, col, b_g, hbf, N);
  // h3 = leaky(h @ W_o1 + b_o1) -> f32
  mgemm_k<1><<<gblocks, 256, 0, stream>>>(hbf, Wt_o1, b_o1, bufF, N, 128);
  // out = h3 @ W_o2 + b_o2
  out_k<<<(N + 63) / 64, 256, 0, stream>>>(bufF, W_o2, b_o2, (float*)d_out, N);
}